// Round 1
// baseline (1094.560 us; speedup 1.0000x reference)
//
#include <hip/hip_runtime.h>

// Problem constants (from reference setup_inputs):
//   x:     [B=16, C=64, H=256, W=256] float32
//   w_off: [2, 64] float32
//   b_off: [2] float32
//   out:   [16, 64, 256, 256] float32
#define BB 16
#define CC 64
#define HH 256
#define WW 256
#define HW (HH * WW)

__global__ __launch_bounds__(256) void dysample_fused(
    const float* __restrict__ x,
    const float* __restrict__ w_off,
    const float* __restrict__ b_off,
    float* __restrict__ out)
{
    // one thread per (b,h,w); lanes consecutive along w
    const int pix = blockIdx.x * blockDim.x + threadIdx.x;
    const int w = pix & (WW - 1);
    const int h = (pix >> 8) & (HH - 1);
    const int b = pix >> 16;

    // stage the tiny weight matrix in LDS
    __shared__ float s_w0[CC];
    __shared__ float s_w1[CC];
    if (threadIdx.x < CC)            s_w0[threadIdx.x]      = w_off[threadIdx.x];
    else if (threadIdx.x < 2 * CC)   s_w1[threadIdx.x - CC] = w_off[threadIdx.x];
    __syncthreads();

    const float* __restrict__ xb = x + (size_t)b * CC * HW;
    const int hw = h * WW + w;

    // ---- pass 1: offset dot product over channels ----
    float acc0 = 0.f, acc1 = 0.f;
#pragma unroll 8
    for (int c = 0; c < CC; ++c) {
        const float v = xb[c * HW + hw];
        acc0 = fmaf(v, s_w0[c], acc0);
        acc1 = fmaf(v, s_w1[c], acc1);
    }
    const float off_x = tanhf(acc0 + b_off[0]) * 0.5f;
    const float off_y = tanhf(acc1 + b_off[1]) * 0.5f;

    // grid coords (align_corners=False, padding zeros)
    const float gx = -1.0f + (float)w * (2.0f / (WW - 1)) + off_x;
    const float gy = -1.0f + (float)h * (2.0f / (HH - 1)) + off_y;
    const float px = ((gx + 1.0f) * (float)WW - 1.0f) * 0.5f;
    const float py = ((gy + 1.0f) * (float)HH - 1.0f) * 0.5f;

    const float x0f = floorf(px);
    const float y0f = floorf(py);
    const float wx1 = px - x0f;
    const float wy1 = py - y0f;
    const float wx0 = 1.0f - wx1;
    const float wy0 = 1.0f - wy1;
    const int x0 = (int)x0f, y0 = (int)y0f;
    const int x1 = x0 + 1,   y1 = y0 + 1;

    const bool vx0 = (x0 >= 0) && (x0 < WW);
    const bool vx1 = (x1 >= 0) && (x1 < WW);
    const bool vy0 = (y0 >= 0) && (y0 < HH);
    const bool vy1 = (y1 >= 0) && (y1 < HH);

    const int cx0 = min(max(x0, 0), WW - 1);
    const int cx1 = min(max(x1, 0), WW - 1);
    const int cy0 = min(max(y0, 0), HH - 1);
    const int cy1 = min(max(y1, 0), HH - 1);

    // fold validity into weights (value*valid == weight*valid since values clamped)
    const float w00 = (vx0 && vy0) ? wx0 * wy0 : 0.f;
    const float w01 = (vx1 && vy0) ? wx1 * wy0 : 0.f;
    const float w10 = (vx0 && vy1) ? wx0 * wy1 : 0.f;
    const float w11 = (vx1 && vy1) ? wx1 * wy1 : 0.f;

    const int i00 = cy0 * WW + cx0;
    const int i01 = cy0 * WW + cx1;
    const int i10 = cy1 * WW + cx0;
    const int i11 = cy1 * WW + cx1;

    // ---- pass 2: per-channel bilinear gather + store ----
    float* __restrict__ ob = out + (size_t)b * CC * HW;
#pragma unroll 4
    for (int c = 0; c < CC; ++c) {
        const float* __restrict__ xc = xb + c * HW;
        float v = w00 * xc[i00];
        v = fmaf(w01, xc[i01], v);
        v = fmaf(w10, xc[i10], v);
        v = fmaf(w11, xc[i11], v);
        ob[c * HW + hw] = v;
    }
}

extern "C" void kernel_launch(void* const* d_in, const int* in_sizes, int n_in,
                              void* d_out, int out_size, void* d_ws, size_t ws_size,
                              hipStream_t stream) {
    const float* x     = (const float*)d_in[0];
    const float* w_off = (const float*)d_in[1];
    const float* b_off = (const float*)d_in[2];
    float* out = (float*)d_out;

    const int total = BB * HH * WW;            // 1,048,576 pixels
    const int block = 256;
    const int grid  = total / block;           // 4096 blocks
    dysample_fused<<<grid, block, 0, stream>>>(x, w_off, b_off, out);
}

// Round 2
// 1019.324 us; speedup vs baseline: 1.0738x; 1.0738x over previous
//
#include <hip/hip_runtime.h>

// x:     [B=16, C=64, H=256, W=256] float32
// w_off: [2, 64] float32
// b_off: [2] float32
// out:   [16, 64, 256, 256] float32
#define BB 16
#define CC 64
#define HH 256
#define WW 256
#define HW (HH * WW)
#define HT 32            // output rows per sampler tile
#define NT (HH / HT)     // 8 tiles per image

// ---------------- kernel 1: offset field -> (px, py) per pixel ----------------
// 4 consecutive pixels per thread (float4 channel reads), fully coalesced.
__global__ __launch_bounds__(256) void k_offsets(
    const float* __restrict__ x,
    const float* __restrict__ w_off,
    const float* __restrict__ b_off,
    float2* __restrict__ pq)
{
    __shared__ float s_w0[CC];
    __shared__ float s_w1[CC];
    if (threadIdx.x < CC)          s_w0[threadIdx.x]      = w_off[threadIdx.x];
    else if (threadIdx.x < 2 * CC) s_w1[threadIdx.x - CC] = w_off[threadIdx.x];
    __syncthreads();

    const int t    = blockIdx.x * blockDim.x + threadIdx.x;
    const int pix0 = t * 4;                 // 4 consecutive w in one row
    const int w = pix0 & (WW - 1);
    const int h = (pix0 >> 8) & (HH - 1);
    const int b = pix0 >> 16;

    const float* __restrict__ xb = x + (size_t)b * CC * HW + h * WW + w;

    float a0[4] = {0.f, 0.f, 0.f, 0.f};
    float a1[4] = {0.f, 0.f, 0.f, 0.f};
#pragma unroll 8
    for (int c = 0; c < CC; ++c) {
        const float4 v = *reinterpret_cast<const float4*>(xb + (size_t)c * HW);
        const float w0 = s_w0[c], w1 = s_w1[c];
        a0[0] = fmaf(v.x, w0, a0[0]); a1[0] = fmaf(v.x, w1, a1[0]);
        a0[1] = fmaf(v.y, w0, a0[1]); a1[1] = fmaf(v.y, w1, a1[1]);
        a0[2] = fmaf(v.z, w0, a0[2]); a1[2] = fmaf(v.z, w1, a1[2]);
        a0[3] = fmaf(v.w, w0, a0[3]); a1[3] = fmaf(v.w, w1, a1[3]);
    }

    const float b0 = b_off[0], b1 = b_off[1];
#pragma unroll
    for (int j = 0; j < 4; ++j) {
        const float offx = tanhf(a0[j] + b0) * 0.5f;
        const float offy = tanhf(a1[j] + b1) * 0.5f;
        const float gx = -1.0f + (float)(w + j) * (2.0f / (WW - 1)) + offx;
        const float gy = -1.0f + (float)h       * (2.0f / (HH - 1)) + offy;
        const float px = ((gx + 1.0f) * (float)WW - 1.0f) * 0.5f;
        const float py = ((gy + 1.0f) * (float)HH - 1.0f) * 0.5f;
        pq[pix0 + j] = make_float2(px, py);
    }
}

// ---------------- kernel 2: per-(b,c,tile) bilinear gather ----------------
// blockIdx = ((b * NT + t) * CC + c)  -> channel fastest: the 64 blocks sharing
// one offset chunk are adjacent; same-plane tiles are 64 apart (same XCD under
// round-robin) so the overlapping row band stays L2-hot.
__global__ __launch_bounds__(256) void k_sample(
    const float* __restrict__ x,
    const float2* __restrict__ pq,
    float* __restrict__ out)
{
    const int bid = blockIdx.x;
    const int c = bid & (CC - 1);
    const int t = (bid >> 6) & (NT - 1);
    const int b = bid >> 9;

    const float* __restrict__ xp = x   + ((size_t)b * CC + c) * HW;
    float* __restrict__       op = out + ((size_t)b * CC + c) * HW + t * HT * WW;
    const float2* __restrict__ pqb = pq + (size_t)b * HW + t * HT * WW;

    const int w = threadIdx.x;

#pragma unroll 2
    for (int k = 0; k < HT; ++k) {
        const float2 p = pqb[k * WW + w];

        const float x0f = floorf(p.x);
        const float y0f = floorf(p.y);
        const float wx1 = p.x - x0f;
        const float wy1 = p.y - y0f;
        const float wx0 = 1.0f - wx1;
        const float wy0 = 1.0f - wy1;
        const int x0 = (int)x0f, y0 = (int)y0f;
        const int x1 = x0 + 1,   y1 = y0 + 1;

        const bool vx0 = (unsigned)x0 < WW;
        const bool vx1 = (unsigned)x1 < WW;
        const bool vy0 = (unsigned)y0 < HH;
        const bool vy1 = (unsigned)y1 < HH;

        const int cx0 = min(max(x0, 0), WW - 1);
        const int cx1 = min(max(x1, 0), WW - 1);
        const int cy0 = min(max(y0, 0), HH - 1);
        const int cy1 = min(max(y1, 0), HH - 1);

        const float w00 = (vx0 && vy0) ? wx0 * wy0 : 0.f;
        const float w01 = (vx1 && vy0) ? wx1 * wy0 : 0.f;
        const float w10 = (vx0 && vy1) ? wx0 * wy1 : 0.f;
        const float w11 = (vx1 && vy1) ? wx1 * wy1 : 0.f;

        float v = w00 * xp[cy0 * WW + cx0];
        v = fmaf(w01, xp[cy0 * WW + cx1], v);
        v = fmaf(w10, xp[cy1 * WW + cx0], v);
        v = fmaf(w11, xp[cy1 * WW + cx1], v);
        op[k * WW + w] = v;
    }
}

extern "C" void kernel_launch(void* const* d_in, const int* in_sizes, int n_in,
                              void* d_out, int out_size, void* d_ws, size_t ws_size,
                              hipStream_t stream) {
    const float* x     = (const float*)d_in[0];
    const float* w_off = (const float*)d_in[1];
    const float* b_off = (const float*)d_in[2];
    float* out = (float*)d_out;
    float2* pq = (float2*)d_ws;   // BB*HW * 8 B = 8 MiB scratch

    const int grid1 = (BB * HW / 4) / 256;   // 1024 blocks
    k_offsets<<<grid1, 256, 0, stream>>>(x, w_off, b_off, pq);

    const int grid2 = BB * NT * CC;          // 8192 blocks
    k_sample<<<grid2, 256, 0, stream>>>(x, pq, out);
}

// Round 3
// 765.902 us; speedup vs baseline: 1.4291x; 1.3309x over previous
//
#include <hip/hip_runtime.h>

// x:     [B=16, C=64, H=256, W=256] float32
// w_off: [2, 64] float32
// b_off: [2] float32
// out:   [16, 64, 256, 256] float32
#define BB 16
#define CC 64
#define HH 256
#define WW 256
#define HW (HH * WW)

// ---------------- kernel 1: offset field -> (px, py) per pixel ----------------
__global__ __launch_bounds__(256) void k_offsets(
    const float* __restrict__ x,
    const float* __restrict__ w_off,
    const float* __restrict__ b_off,
    float2* __restrict__ pq)
{
    __shared__ float s_w0[CC];
    __shared__ float s_w1[CC];
    if (threadIdx.x < CC)          s_w0[threadIdx.x]      = w_off[threadIdx.x];
    else if (threadIdx.x < 2 * CC) s_w1[threadIdx.x - CC] = w_off[threadIdx.x];
    __syncthreads();

    const int t    = blockIdx.x * blockDim.x + threadIdx.x;
    const int pix0 = t * 4;                 // 4 consecutive w in one row
    const int w = pix0 & (WW - 1);
    const int h = (pix0 >> 8) & (HH - 1);
    const int b = pix0 >> 16;

    const float* __restrict__ xb = x + (size_t)b * CC * HW + h * WW + w;

    float a0[4] = {0.f, 0.f, 0.f, 0.f};
    float a1[4] = {0.f, 0.f, 0.f, 0.f};
#pragma unroll 8
    for (int c = 0; c < CC; ++c) {
        const float4 v = *reinterpret_cast<const float4*>(xb + (size_t)c * HW);
        const float w0 = s_w0[c], w1 = s_w1[c];
        a0[0] = fmaf(v.x, w0, a0[0]); a1[0] = fmaf(v.x, w1, a1[0]);
        a0[1] = fmaf(v.y, w0, a0[1]); a1[1] = fmaf(v.y, w1, a1[1]);
        a0[2] = fmaf(v.z, w0, a0[2]); a1[2] = fmaf(v.z, w1, a1[2]);
        a0[3] = fmaf(v.w, w0, a0[3]); a1[3] = fmaf(v.w, w1, a1[3]);
    }

    const float b0 = b_off[0], b1 = b_off[1];
#pragma unroll
    for (int j = 0; j < 4; ++j) {
        const float offx = tanhf(a0[j] + b0) * 0.5f;
        const float offy = tanhf(a1[j] + b1) * 0.5f;
        const float gx = -1.0f + (float)(w + j) * (2.0f / (WW - 1)) + offx;
        const float gy = -1.0f + (float)h       * (2.0f / (HH - 1)) + offy;
        const float px = ((gx + 1.0f) * (float)WW - 1.0f) * 0.5f;
        const float py = ((gy + 1.0f) * (float)HH - 1.0f) * 0.5f;
        pq[pix0 + j] = make_float2(px, py);
    }
}

// ---------------- kernel 2: per-(b,c) plane bilinear gather ----------------
// One block per (b,c): walks all 256 rows top-to-bottom -> rolling ~128-row
// gather band per block. 1024 blocks = 4/CU -> ~16 MB band working set per
// XCD, ~128 MB device-wide (fits L3). Row loop unrolled 4x with all 16
// corner loads issued before any use -> ~16 outstanding loads/wave.
__global__ __launch_bounds__(256, 4) void k_sample(
    const float* __restrict__ x,
    const float2* __restrict__ pq,
    float* __restrict__ out)
{
    const int bid = blockIdx.x;
    const int c = bid & (CC - 1);
    const int b = bid >> 6;

    const float* __restrict__ xp = x   + ((size_t)b * CC + c) * HW;
    float* __restrict__       op = out + ((size_t)b * CC + c) * HW;
    const float2* __restrict__ pqb = pq + (size_t)b * HW;

    const int w = threadIdx.x;

    for (int k0 = 0; k0 < HH; k0 += 4) {
        // --- phase 1: read offsets, build indices & weights for 4 rows ---
        int   i00[4], i01[4], i10[4], i11[4];
        float w00[4], w01[4], w10[4], w11[4];
#pragma unroll
        for (int j = 0; j < 4; ++j) {
            const float2 p = pqb[(k0 + j) * WW + w];
            const float x0f = floorf(p.x);
            const float y0f = floorf(p.y);
            const float wx1 = p.x - x0f;
            const float wy1 = p.y - y0f;
            const float wx0 = 1.0f - wx1;
            const float wy0 = 1.0f - wy1;
            const int x0 = (int)x0f, y0 = (int)y0f;
            const int x1 = x0 + 1,   y1 = y0 + 1;

            const bool vx0 = (unsigned)x0 < WW;
            const bool vx1 = (unsigned)x1 < WW;
            const bool vy0 = (unsigned)y0 < HH;
            const bool vy1 = (unsigned)y1 < HH;

            const int cx0 = min(max(x0, 0), WW - 1);
            const int cx1 = min(max(x1, 0), WW - 1);
            const int cy0 = min(max(y0, 0), HH - 1);
            const int cy1 = min(max(y1, 0), HH - 1);

            w00[j] = (vx0 && vy0) ? wx0 * wy0 : 0.f;
            w01[j] = (vx1 && vy0) ? wx1 * wy0 : 0.f;
            w10[j] = (vx0 && vy1) ? wx0 * wy1 : 0.f;
            w11[j] = (vx1 && vy1) ? wx1 * wy1 : 0.f;

            i00[j] = cy0 * WW + cx0;
            i01[j] = cy0 * WW + cx1;
            i10[j] = cy1 * WW + cx0;
            i11[j] = cy1 * WW + cx1;
        }

        // --- phase 2: issue all 16 gathers ---
        float v00[4], v01[4], v10[4], v11[4];
#pragma unroll
        for (int j = 0; j < 4; ++j) v00[j] = xp[i00[j]];
#pragma unroll
        for (int j = 0; j < 4; ++j) v01[j] = xp[i01[j]];
#pragma unroll
        for (int j = 0; j < 4; ++j) v10[j] = xp[i10[j]];
#pragma unroll
        for (int j = 0; j < 4; ++j) v11[j] = xp[i11[j]];

        // --- phase 3: blend + non-temporal store ---
#pragma unroll
        for (int j = 0; j < 4; ++j) {
            float v = w00[j] * v00[j];
            v = fmaf(w01[j], v01[j], v);
            v = fmaf(w10[j], v10[j], v);
            v = fmaf(w11[j], v11[j], v);
            __builtin_nontemporal_store(v, &op[(k0 + j) * WW + w]);
        }
    }
}

extern "C" void kernel_launch(void* const* d_in, const int* in_sizes, int n_in,
                              void* d_out, int out_size, void* d_ws, size_t ws_size,
                              hipStream_t stream) {
    const float* x     = (const float*)d_in[0];
    const float* w_off = (const float*)d_in[1];
    const float* b_off = (const float*)d_in[2];
    float* out = (float*)d_out;
    float2* pq = (float2*)d_ws;   // BB*HW * 8 B = 8 MiB scratch

    const int grid1 = (BB * HW / 4) / 256;   // 1024 blocks
    k_offsets<<<grid1, 256, 0, stream>>>(x, w_off, b_off, pq);

    const int grid2 = BB * CC;               // 1024 blocks, one per (b,c) plane
    k_sample<<<grid2, 256, 0, stream>>>(x, pq, out);
}

// Round 4
// 389.515 us; speedup vs baseline: 2.8101x; 1.9663x over previous
//
#include <hip/hip_runtime.h>

// x:     [B=16, C=64, H=256, W=256] float32
// w_off: [2, 64] float32
// b_off: [2] float32
// out:   [16, 64, 256, 256] float32
#define BB 16
#define CC 64
#define HH 256
#define WW 256
#define HW (HH * WW)

// ============================ NEW PATH ============================
// ws layout: xt [B][H][W][C] floats (268,435,456 B) then pq [B][H][W] float2 (8,388,608 B)
#define XT_BYTES (268435456ULL)
#define NEED_WS  (XT_BYTES + 8388608ULL)

// ---- kernel 1: read x coalesced; dot -> pq; transpose -> xt[B,H,W,C] ----
// one block per (b,row). LDS [64][257] padded: write s[c][t] coalesced,
// read s[c][p] strided (conflict-free via +1 pad).
__global__ __launch_bounds__(256) void k_prep(
    const float* __restrict__ x,
    const float* __restrict__ w_off,
    const float* __restrict__ b_off,
    float* __restrict__ xt,
    float2* __restrict__ pq)
{
    __shared__ float s[CC][WW + 1];
    __shared__ float sw0[CC], sw1[CC];
    const int t = threadIdx.x;
    if (t < CC)          sw0[t]      = w_off[t];
    else if (t < 2 * CC) sw1[t - CC] = w_off[t];
    __syncthreads();

    const int row = blockIdx.x & (HH - 1);
    const int b   = blockIdx.x >> 8;

    const float* __restrict__ xb = x + (size_t)b * CC * HW + row * WW + t;

    float a0 = 0.f, a1 = 0.f;
#pragma unroll 8
    for (int c = 0; c < CC; ++c) {
        const float v = xb[(size_t)c * HW];
        s[c][t] = v;
        a0 = fmaf(v, sw0[c], a0);
        a1 = fmaf(v, sw1[c], a1);
    }

    // offsets -> sample coords
    const float offx = tanhf(a0 + b_off[0]) * 0.5f;
    const float offy = tanhf(a1 + b_off[1]) * 0.5f;
    const float gx = -1.0f + (float)t   * (2.0f / (WW - 1)) + offx;
    const float gy = -1.0f + (float)row * (2.0f / (HH - 1)) + offy;
    const float px = ((gx + 1.0f) * (float)WW - 1.0f) * 0.5f;
    const float py = ((gy + 1.0f) * (float)HH - 1.0f) * 0.5f;
    pq[(size_t)b * HW + row * WW + t] = make_float2(px, py);

    __syncthreads();

    // transposed write-out: thread t -> pixel p = t>>2, sub = t&3.
    // store #k: float4 at elem pp*64 + k*16 + sub*4 = channels k*16+sub*4 ..+3
    // -> per instruction: 16 full 64B lines (fully coalesced 1KB).
    const int p   = t >> 2;
    const int sub = t & 3;
    float* __restrict__ xto = xt + ((size_t)b * HW + (size_t)row * WW) * CC;
#pragma unroll
    for (int g = 0; g < 4; ++g) {
        const int pp = g * 64 + p;
#pragma unroll
        for (int k = 0; k < 4; ++k) {
            const int c0 = k * 16 + sub * 4;
            float4 v;
            v.x = s[c0 + 0][pp];
            v.y = s[c0 + 1][pp];
            v.z = s[c0 + 2][pp];
            v.w = s[c0 + 3][pp];
            *reinterpret_cast<float4*>(xto + (size_t)pp * CC + c0) = v;
        }
    }
}

// ---- kernel 2: bilinear gather from xt (256B/corner contiguous) ----
// one block per (b,row,half): 128 pixels. thread t: pixel p=t&127,
// channels ch0=(t>>7)*32 .. +31 as 8 float4 chunks. Results staged in
// padded LDS, written to out[B,C,H,W] coalesced. XCD-chunked swizzle.
__global__ __launch_bounds__(256) void k_sample2(
    const float* __restrict__ xt,
    const float2* __restrict__ pq,
    float* __restrict__ out)
{
    // 8192 blocks = 8 XCDs x 1024: lb = (raw&7)*1024 + raw>>3 (bijective);
    // each XCD gets 1024 consecutive lb = 512 consecutive rows (2 batches).
    const int raw = blockIdx.x;
    const int lb  = (raw & 7) * 1024 + (raw >> 3);
    const int half = lb & 1;
    const int row  = (lb >> 1) & (HH - 1);
    const int b    = lb >> 9;

    __shared__ float so[CC][129];

    const int t   = threadIdx.x;
    const int p   = t & 127;
    const int ch0 = (t >> 7) * 32;
    const int p0  = half * 128;

    const float2 pr = pq[(size_t)b * HW + row * WW + p0 + p];

    const float x0f = floorf(pr.x);
    const float y0f = floorf(pr.y);
    const float wx1 = pr.x - x0f;
    const float wy1 = pr.y - y0f;
    const float wx0 = 1.0f - wx1;
    const float wy0 = 1.0f - wy1;
    const int x0 = (int)x0f, y0 = (int)y0f;
    const int x1 = x0 + 1,   y1 = y0 + 1;

    const bool vx0 = (unsigned)x0 < WW;
    const bool vx1 = (unsigned)x1 < WW;
    const bool vy0 = (unsigned)y0 < HH;
    const bool vy1 = (unsigned)y1 < HH;

    const int cx0 = min(max(x0, 0), WW - 1);
    const int cx1 = min(max(x1, 0), WW - 1);
    const int cy0 = min(max(y0, 0), HH - 1);
    const int cy1 = min(max(y1, 0), HH - 1);

    const float w00 = (vx0 && vy0) ? wx0 * wy0 : 0.f;
    const float w01 = (vx1 && vy0) ? wx1 * wy0 : 0.f;
    const float w10 = (vx0 && vy1) ? wx0 * wy1 : 0.f;
    const float w11 = (vx1 && vy1) ? wx1 * wy1 : 0.f;

    const float* __restrict__ xb = xt + (size_t)b * HW * CC;
    const size_t c00 = (size_t)(cy0 * WW + cx0) * CC + ch0;
    const size_t c01 = (size_t)(cy0 * WW + cx1) * CC + ch0;
    const size_t c10 = (size_t)(cy1 * WW + cx0) * CC + ch0;
    const size_t c11 = (size_t)(cy1 * WW + cx1) * CC + ch0;

#pragma unroll
    for (int k = 0; k < 8; k += 2) {
        // issue 8 float4 gathers before any use
        const float4 a0 = *reinterpret_cast<const float4*>(xb + c00 + k * 4);
        const float4 b0 = *reinterpret_cast<const float4*>(xb + c01 + k * 4);
        const float4 g0 = *reinterpret_cast<const float4*>(xb + c10 + k * 4);
        const float4 d0 = *reinterpret_cast<const float4*>(xb + c11 + k * 4);
        const float4 a1 = *reinterpret_cast<const float4*>(xb + c00 + k * 4 + 4);
        const float4 b1 = *reinterpret_cast<const float4*>(xb + c01 + k * 4 + 4);
        const float4 g1 = *reinterpret_cast<const float4*>(xb + c10 + k * 4 + 4);
        const float4 d1 = *reinterpret_cast<const float4*>(xb + c11 + k * 4 + 4);

        float4 r0, r1;
        r0.x = fmaf(w11, d0.x, fmaf(w10, g0.x, fmaf(w01, b0.x, w00 * a0.x)));
        r0.y = fmaf(w11, d0.y, fmaf(w10, g0.y, fmaf(w01, b0.y, w00 * a0.y)));
        r0.z = fmaf(w11, d0.z, fmaf(w10, g0.z, fmaf(w01, b0.z, w00 * a0.z)));
        r0.w = fmaf(w11, d0.w, fmaf(w10, g0.w, fmaf(w01, b0.w, w00 * a0.w)));
        r1.x = fmaf(w11, d1.x, fmaf(w10, g1.x, fmaf(w01, b1.x, w00 * a1.x)));
        r1.y = fmaf(w11, d1.y, fmaf(w10, g1.y, fmaf(w01, b1.y, w00 * a1.y)));
        r1.z = fmaf(w11, d1.z, fmaf(w10, g1.z, fmaf(w01, b1.z, w00 * a1.z)));
        r1.w = fmaf(w11, d1.w, fmaf(w10, g1.w, fmaf(w01, b1.w, w00 * a1.w)));

        const int c = ch0 + k * 4;
        so[c + 0][p] = r0.x; so[c + 1][p] = r0.y;
        so[c + 2][p] = r0.z; so[c + 3][p] = r0.w;
        so[c + 4][p] = r1.x; so[c + 5][p] = r1.y;
        so[c + 6][p] = r1.z; so[c + 7][p] = r1.w;
    }

    __syncthreads();

    // coalesced write-out: per instruction each wave writes 64 consecutive
    // floats of one channel row.
    float* __restrict__ ob = out + (size_t)b * CC * HW + row * WW + p0;
#pragma unroll 8
    for (int j = 0; j < 32; ++j) {
        const int c = ch0 + j;
        __builtin_nontemporal_store(so[c][p], &ob[(size_t)c * HW + p]);
    }
}

// ============================ FALLBACK PATH (R3, verified) ============================
__global__ __launch_bounds__(256) void k_offsets(
    const float* __restrict__ x,
    const float* __restrict__ w_off,
    const float* __restrict__ b_off,
    float2* __restrict__ pq)
{
    __shared__ float s_w0[CC];
    __shared__ float s_w1[CC];
    if (threadIdx.x < CC)          s_w0[threadIdx.x]      = w_off[threadIdx.x];
    else if (threadIdx.x < 2 * CC) s_w1[threadIdx.x - CC] = w_off[threadIdx.x];
    __syncthreads();

    const int t    = blockIdx.x * blockDim.x + threadIdx.x;
    const int pix0 = t * 4;
    const int w = pix0 & (WW - 1);
    const int h = (pix0 >> 8) & (HH - 1);
    const int b = pix0 >> 16;

    const float* __restrict__ xb = x + (size_t)b * CC * HW + h * WW + w;

    float a0[4] = {0.f, 0.f, 0.f, 0.f};
    float a1[4] = {0.f, 0.f, 0.f, 0.f};
#pragma unroll 8
    for (int c = 0; c < CC; ++c) {
        const float4 v = *reinterpret_cast<const float4*>(xb + (size_t)c * HW);
        const float w0 = s_w0[c], w1 = s_w1[c];
        a0[0] = fmaf(v.x, w0, a0[0]); a1[0] = fmaf(v.x, w1, a1[0]);
        a0[1] = fmaf(v.y, w0, a0[1]); a1[1] = fmaf(v.y, w1, a1[1]);
        a0[2] = fmaf(v.z, w0, a0[2]); a1[2] = fmaf(v.z, w1, a1[2]);
        a0[3] = fmaf(v.w, w0, a0[3]); a1[3] = fmaf(v.w, w1, a1[3]);
    }

    const float b0 = b_off[0], b1 = b_off[1];
#pragma unroll
    for (int j = 0; j < 4; ++j) {
        const float offx = tanhf(a0[j] + b0) * 0.5f;
        const float offy = tanhf(a1[j] + b1) * 0.5f;
        const float gx = -1.0f + (float)(w + j) * (2.0f / (WW - 1)) + offx;
        const float gy = -1.0f + (float)h       * (2.0f / (HH - 1)) + offy;
        const float px = ((gx + 1.0f) * (float)WW - 1.0f) * 0.5f;
        const float py = ((gy + 1.0f) * (float)HH - 1.0f) * 0.5f;
        pq[pix0 + j] = make_float2(px, py);
    }
}

__global__ __launch_bounds__(256, 4) void k_sample(
    const float* __restrict__ x,
    const float2* __restrict__ pq,
    float* __restrict__ out)
{
    const int bid = blockIdx.x;
    const int c = bid & (CC - 1);
    const int b = bid >> 6;

    const float* __restrict__ xp = x   + ((size_t)b * CC + c) * HW;
    float* __restrict__       op = out + ((size_t)b * CC + c) * HW;
    const float2* __restrict__ pqb = pq + (size_t)b * HW;

    const int w = threadIdx.x;

    for (int k0 = 0; k0 < HH; k0 += 4) {
        int   i00[4], i01[4], i10[4], i11[4];
        float w00[4], w01[4], w10[4], w11[4];
#pragma unroll
        for (int j = 0; j < 4; ++j) {
            const float2 p = pqb[(k0 + j) * WW + w];
            const float x0f = floorf(p.x);
            const float y0f = floorf(p.y);
            const float wx1 = p.x - x0f;
            const float wy1 = p.y - y0f;
            const float wx0 = 1.0f - wx1;
            const float wy0 = 1.0f - wy1;
            const int x0 = (int)x0f, y0 = (int)y0f;
            const int x1 = x0 + 1,   y1 = y0 + 1;
            const bool vx0 = (unsigned)x0 < WW;
            const bool vx1 = (unsigned)x1 < WW;
            const bool vy0 = (unsigned)y0 < HH;
            const bool vy1 = (unsigned)y1 < HH;
            const int cx0 = min(max(x0, 0), WW - 1);
            const int cx1 = min(max(x1, 0), WW - 1);
            const int cy0 = min(max(y0, 0), HH - 1);
            const int cy1 = min(max(y1, 0), HH - 1);
            w00[j] = (vx0 && vy0) ? wx0 * wy0 : 0.f;
            w01[j] = (vx1 && vy0) ? wx1 * wy0 : 0.f;
            w10[j] = (vx0 && vy1) ? wx0 * wy1 : 0.f;
            w11[j] = (vx1 && vy1) ? wx1 * wy1 : 0.f;
            i00[j] = cy0 * WW + cx0;
            i01[j] = cy0 * WW + cx1;
            i10[j] = cy1 * WW + cx0;
            i11[j] = cy1 * WW + cx1;
        }
        float v00[4], v01[4], v10[4], v11[4];
#pragma unroll
        for (int j = 0; j < 4; ++j) v00[j] = xp[i00[j]];
#pragma unroll
        for (int j = 0; j < 4; ++j) v01[j] = xp[i01[j]];
#pragma unroll
        for (int j = 0; j < 4; ++j) v10[j] = xp[i10[j]];
#pragma unroll
        for (int j = 0; j < 4; ++j) v11[j] = xp[i11[j]];
#pragma unroll
        for (int j = 0; j < 4; ++j) {
            float v = w00[j] * v00[j];
            v = fmaf(w01[j], v01[j], v);
            v = fmaf(w10[j], v10[j], v);
            v = fmaf(w11[j], v11[j], v);
            __builtin_nontemporal_store(v, &op[(k0 + j) * WW + w]);
        }
    }
}

extern "C" void kernel_launch(void* const* d_in, const int* in_sizes, int n_in,
                              void* d_out, int out_size, void* d_ws, size_t ws_size,
                              hipStream_t stream) {
    const float* x     = (const float*)d_in[0];
    const float* w_off = (const float*)d_in[1];
    const float* b_off = (const float*)d_in[2];
    float* out = (float*)d_out;

    if (ws_size >= NEED_WS) {
        float*  xt = (float*)d_ws;
        float2* pq = (float2*)((char*)d_ws + XT_BYTES);
        k_prep<<<BB * HH, 256, 0, stream>>>(x, w_off, b_off, xt, pq);
        k_sample2<<<BB * HH * 2, 256, 0, stream>>>(xt, pq, out);
    } else {
        float2* pq = (float2*)d_ws;  // 8 MiB
        const int grid1 = (BB * HW / 4) / 256;
        k_offsets<<<grid1, 256, 0, stream>>>(x, w_off, b_off, pq);
        k_sample<<<BB * CC, 256, 0, stream>>>(x, pq, out);
    }
}

// Round 6
// 201.963 us; speedup vs baseline: 5.4196x; 1.9286x over previous
//
#include <hip/hip_runtime.h>

// x:     [B=16, C=64, H=256, W=256] float32
// w_off: [2, 64] float32
// b_off: [2] float32
// out:   [16, 64, 256, 256] float32
#define BB 16
#define CC 64
#define HH 256
#define WW 256
#define HW (HH * WW)

// ws layout: xt bf16 [B][H][W][C] = 16*65536*64*2 B = 134,217,728 B, then pq float2 (8 MiB)
#define XT_BYTES 134217728ULL
#define NEED_WS  (XT_BYTES + 8388608ULL)

typedef float  fx4 __attribute__((ext_vector_type(4)));   // native vec for nontemporal store

__device__ __forceinline__ unsigned int f2bf(float f) {
    unsigned int u = __float_as_uint(f);
    u += 0x7FFFu + ((u >> 16) & 1u);          // round-to-nearest-even
    return u >> 16;
}
__device__ __forceinline__ float bflo(unsigned int w) { return __uint_as_float(w << 16); }
__device__ __forceinline__ float bfhi(unsigned int w) { return __uint_as_float(w & 0xFFFF0000u); }

// ---- kernel 1: read x coalesced; dot -> pq; transpose -> xt[B,H,W,C] bf16 ----
__global__ __launch_bounds__(256) void k_prep(
    const float* __restrict__ x,
    const float* __restrict__ w_off,
    const float* __restrict__ b_off,
    unsigned int* __restrict__ xt,       // 32 uints (64 bf16) per pixel
    float2* __restrict__ pq)
{
    __shared__ float s[CC][WW + 1];
    __shared__ float sw0[CC], sw1[CC];
    const int t = threadIdx.x;
    if (t < CC)          sw0[t]      = w_off[t];
    else if (t < 2 * CC) sw1[t - CC] = w_off[t];
    __syncthreads();

    const int row = blockIdx.x & (HH - 1);
    const int b   = blockIdx.x >> 8;

    const float* __restrict__ xb = x + (size_t)b * CC * HW + row * WW + t;

    float a0 = 0.f, a1 = 0.f;
#pragma unroll 8
    for (int c = 0; c < CC; ++c) {
        const float v = xb[(size_t)c * HW];
        s[c][t] = v;
        a0 = fmaf(v, sw0[c], a0);
        a1 = fmaf(v, sw1[c], a1);
    }

    const float offx = tanhf(a0 + b_off[0]) * 0.5f;
    const float offy = tanhf(a1 + b_off[1]) * 0.5f;
    const float gx = -1.0f + (float)t   * (2.0f / (WW - 1)) + offx;
    const float gy = -1.0f + (float)row * (2.0f / (HH - 1)) + offy;
    const float px = ((gx + 1.0f) * (float)WW - 1.0f) * 0.5f;
    const float py = ((gy + 1.0f) * (float)HH - 1.0f) * 0.5f;
    pq[(size_t)b * HW + row * WW + t] = make_float2(px, py);

    __syncthreads();

    // transposed bf16 write-out: thread t -> pixel p=t>>2, channel block sub=t&3 (16 ch = 32 B).
    const int p   = t >> 2;
    const int sub = t & 3;
    unsigned int* __restrict__ xto = xt + ((size_t)b * HW + (size_t)row * WW) * 32;
#pragma unroll
    for (int g = 0; g < 4; ++g) {
        const int pp = g * 64 + p;
        const int c0 = sub * 16;
        unsigned int wv[8];
#pragma unroll
        for (int k = 0; k < 8; ++k) {
            wv[k] = f2bf(s[c0 + 2 * k][pp]) | (f2bf(s[c0 + 2 * k + 1][pp]) << 16);
        }
        unsigned int* dst = xto + (size_t)pp * 32 + sub * 8;
        *reinterpret_cast<uint4*>(dst)     = make_uint4(wv[0], wv[1], wv[2], wv[3]);
        *reinterpret_cast<uint4*>(dst + 4) = make_uint4(wv[4], wv[5], wv[6], wv[7]);
    }
}

// ---- kernel 2: lane-cooperative bilinear gather from bf16 xt ----
// 64-px blocks: grid 16384, XCD-chunked. Wave: 8 pixel-slots x 8 channel-octets;
// per pixel-corner the 8 lanes fetch one contiguous 128 B segment.
__global__ __launch_bounds__(256) void k_sample3(
    const unsigned int* __restrict__ xt,
    const float2* __restrict__ pq,
    float* __restrict__ out)
{
    const int raw = blockIdx.x;
    const int lb  = (raw & 7) * 2048 + (raw >> 3);   // bijective XCD chunking
    const int quarter = lb & 3;
    const int row     = (lb >> 2) & (HH - 1);
    const int b       = lb >> 10;

    __shared__ float so[CC][65];     // [channel][pixel], bank = (c+px)%32 both ways

    const int t  = threadIdx.x;
    const int l8 = t & 7;            // channel octet: channels l8*8 .. +7
    const int ps = t >> 3;           // pixel slot 0..31
    const int px0 = quarter * 64;

    const unsigned int* __restrict__ xb = xt + (size_t)b * HW * 32;
    const float2* __restrict__ pqr = pq + (size_t)b * HW + row * WW + px0;

    // ---- both pixels: coords ----
    const int pxlA = ps;
    const int pxlB = 32 + ps;
    const float2 prA = pqr[pxlA];
    const float2 prB = pqr[pxlB];

#define COORDS(pr, W00, W01, W10, W11, I00, I01, I10, I11)                          \
    {                                                                               \
        const float x0f = floorf(pr.x), y0f = floorf(pr.y);                         \
        const float wx1 = pr.x - x0f,  wy1 = pr.y - y0f;                            \
        const float wx0 = 1.f - wx1,   wy0 = 1.f - wy1;                             \
        const int x0 = (int)x0f, y0 = (int)y0f, x1 = x0 + 1, y1 = y0 + 1;           \
        const bool vx0 = (unsigned)x0 < WW, vx1 = (unsigned)x1 < WW;                \
        const bool vy0 = (unsigned)y0 < HH, vy1 = (unsigned)y1 < HH;                \
        const int cx0 = min(max(x0, 0), WW - 1), cx1 = min(max(x1, 0), WW - 1);     \
        const int cy0 = min(max(y0, 0), HH - 1), cy1 = min(max(y1, 0), HH - 1);     \
        W00 = (vx0 && vy0) ? wx0 * wy0 : 0.f;                                       \
        W01 = (vx1 && vy0) ? wx1 * wy0 : 0.f;                                       \
        W10 = (vx0 && vy1) ? wx0 * wy1 : 0.f;                                       \
        W11 = (vx1 && vy1) ? wx1 * wy1 : 0.f;                                       \
        I00 = (size_t)(cy0 * WW + cx0) * 32 + l8 * 4;                               \
        I01 = (size_t)(cy0 * WW + cx1) * 32 + l8 * 4;                               \
        I10 = (size_t)(cy1 * WW + cx0) * 32 + l8 * 4;                               \
        I11 = (size_t)(cy1 * WW + cx1) * 32 + l8 * 4;                               \
    }

    float wA00, wA01, wA10, wA11, wB00, wB01, wB10, wB11;
    size_t iA00, iA01, iA10, iA11, iB00, iB01, iB10, iB11;
    COORDS(prA, wA00, wA01, wA10, wA11, iA00, iA01, iA10, iA11)
    COORDS(prB, wB00, wB01, wB10, wB11, iB00, iB01, iB10, iB11)

    // ---- issue all 8 cooperative gathers (128 B per pixel-corner) ----
    const uint4 vA00 = *reinterpret_cast<const uint4*>(xb + iA00);
    const uint4 vA01 = *reinterpret_cast<const uint4*>(xb + iA01);
    const uint4 vA10 = *reinterpret_cast<const uint4*>(xb + iA10);
    const uint4 vA11 = *reinterpret_cast<const uint4*>(xb + iA11);
    const uint4 vB00 = *reinterpret_cast<const uint4*>(xb + iB00);
    const uint4 vB01 = *reinterpret_cast<const uint4*>(xb + iB01);
    const uint4 vB10 = *reinterpret_cast<const uint4*>(xb + iB10);
    const uint4 vB11 = *reinterpret_cast<const uint4*>(xb + iB11);

    const int c8 = l8 * 8;

#define BLEND_STORE(V00, V01, V10, V11, W00, W01, W10, W11, PXL)                    \
    {                                                                               \
        float f0 = W00 * bflo(V00.x); float f1 = W00 * bfhi(V00.x);                 \
        float f2 = W00 * bflo(V00.y); float f3 = W00 * bfhi(V00.y);                 \
        float f4 = W00 * bflo(V00.z); float f5 = W00 * bfhi(V00.z);                 \
        float f6 = W00 * bflo(V00.w); float f7 = W00 * bfhi(V00.w);                 \
        f0 = fmaf(W01, bflo(V01.x), f0); f1 = fmaf(W01, bfhi(V01.x), f1);           \
        f2 = fmaf(W01, bflo(V01.y), f2); f3 = fmaf(W01, bfhi(V01.y), f3);           \
        f4 = fmaf(W01, bflo(V01.z), f4); f5 = fmaf(W01, bfhi(V01.z), f5);           \
        f6 = fmaf(W01, bflo(V01.w), f6); f7 = fmaf(W01, bfhi(V01.w), f7);           \
        f0 = fmaf(W10, bflo(V10.x), f0); f1 = fmaf(W10, bfhi(V10.x), f1);           \
        f2 = fmaf(W10, bflo(V10.y), f2); f3 = fmaf(W10, bfhi(V10.y), f3);           \
        f4 = fmaf(W10, bflo(V10.z), f4); f5 = fmaf(W10, bfhi(V10.z), f5);           \
        f6 = fmaf(W10, bflo(V10.w), f6); f7 = fmaf(W10, bfhi(V10.w), f7);           \
        f0 = fmaf(W11, bflo(V11.x), f0); f1 = fmaf(W11, bfhi(V11.x), f1);           \
        f2 = fmaf(W11, bflo(V11.y), f2); f3 = fmaf(W11, bfhi(V11.y), f3);           \
        f4 = fmaf(W11, bflo(V11.z), f4); f5 = fmaf(W11, bfhi(V11.z), f5);           \
        f6 = fmaf(W11, bflo(V11.w), f6); f7 = fmaf(W11, bfhi(V11.w), f7);           \
        so[c8 + 0][PXL] = f0; so[c8 + 1][PXL] = f1;                                 \
        so[c8 + 2][PXL] = f2; so[c8 + 3][PXL] = f3;                                 \
        so[c8 + 4][PXL] = f4; so[c8 + 5][PXL] = f5;                                 \
        so[c8 + 6][PXL] = f6; so[c8 + 7][PXL] = f7;                                 \
    }

    BLEND_STORE(vA00, vA01, vA10, vA11, wA00, wA01, wA10, wA11, pxlA)
    BLEND_STORE(vB00, vB01, vB10, vB11, wB00, wB01, wB10, wB11, pxlB)

    __syncthreads();

    // ---- coalesced write-out: float4 along w, 4 channel segments per instr ----
    const int p  = t & 15;          // pixel quad 4p..4p+3
    const int cg = (t >> 4) & 3;
    const int wv = t >> 6;
    float* __restrict__ ob = out + (size_t)b * CC * HW + row * WW + px0;
#pragma unroll
    for (int it = 0; it < 4; ++it) {
        const int c = wv * 16 + it * 4 + cg;
        fx4 r;
        r.x = so[c][4 * p + 0];
        r.y = so[c][4 * p + 1];
        r.z = so[c][4 * p + 2];
        r.w = so[c][4 * p + 3];
        __builtin_nontemporal_store(r, reinterpret_cast<fx4*>(ob + (size_t)c * HW + 4 * p));
    }
}

// ============================ FALLBACK PATH (R3, verified) ============================
__global__ __launch_bounds__(256) void k_offsets(
    const float* __restrict__ x,
    const float* __restrict__ w_off,
    const float* __restrict__ b_off,
    float2* __restrict__ pq)
{
    __shared__ float s_w0[CC];
    __shared__ float s_w1[CC];
    if (threadIdx.x < CC)          s_w0[threadIdx.x]      = w_off[threadIdx.x];
    else if (threadIdx.x < 2 * CC) s_w1[threadIdx.x - CC] = w_off[threadIdx.x];
    __syncthreads();

    const int t    = blockIdx.x * blockDim.x + threadIdx.x;
    const int pix0 = t * 4;
    const int w = pix0 & (WW - 1);
    const int h = (pix0 >> 8) & (HH - 1);
    const int b = pix0 >> 16;

    const float* __restrict__ xb = x + (size_t)b * CC * HW + h * WW + w;

    float a0[4] = {0.f, 0.f, 0.f, 0.f};
    float a1[4] = {0.f, 0.f, 0.f, 0.f};
#pragma unroll 8
    for (int c = 0; c < CC; ++c) {
        const float4 v = *reinterpret_cast<const float4*>(xb + (size_t)c * HW);
        const float w0 = s_w0[c], w1 = s_w1[c];
        a0[0] = fmaf(v.x, w0, a0[0]); a1[0] = fmaf(v.x, w1, a1[0]);
        a0[1] = fmaf(v.y, w0, a0[1]); a1[1] = fmaf(v.y, w1, a1[1]);
        a0[2] = fmaf(v.z, w0, a0[2]); a1[2] = fmaf(v.z, w1, a1[2]);
        a0[3] = fmaf(v.w, w0, a0[3]); a1[3] = fmaf(v.w, w1, a1[3]);
    }

    const float b0 = b_off[0], b1 = b_off[1];
#pragma unroll
    for (int j = 0; j < 4; ++j) {
        const float offx = tanhf(a0[j] + b0) * 0.5f;
        const float offy = tanhf(a1[j] + b1) * 0.5f;
        const float gx = -1.0f + (float)(w + j) * (2.0f / (WW - 1)) + offx;
        const float gy = -1.0f + (float)h       * (2.0f / (HH - 1)) + offy;
        const float px = ((gx + 1.0f) * (float)WW - 1.0f) * 0.5f;
        const float py = ((gy + 1.0f) * (float)HH - 1.0f) * 0.5f;
        pq[pix0 + j] = make_float2(px, py);
    }
}

__global__ __launch_bounds__(256, 4) void k_sample(
    const float* __restrict__ x,
    const float2* __restrict__ pq,
    float* __restrict__ out)
{
    const int bid = blockIdx.x;
    const int c = bid & (CC - 1);
    const int b = bid >> 6;

    const float* __restrict__ xp = x   + ((size_t)b * CC + c) * HW;
    float* __restrict__       op = out + ((size_t)b * CC + c) * HW;
    const float2* __restrict__ pqb = pq + (size_t)b * HW;

    const int w = threadIdx.x;

    for (int k0 = 0; k0 < HH; k0 += 4) {
        int   i00[4], i01[4], i10[4], i11[4];
        float w00[4], w01[4], w10[4], w11[4];
#pragma unroll
        for (int j = 0; j < 4; ++j) {
            const float2 p = pqb[(k0 + j) * WW + w];
            const float x0f = floorf(p.x);
            const float y0f = floorf(p.y);
            const float wx1 = p.x - x0f;
            const float wy1 = p.y - y0f;
            const float wx0 = 1.0f - wx1;
            const float wy0 = 1.0f - wy1;
            const int x0 = (int)x0f, y0 = (int)y0f;
            const int x1 = x0 + 1,   y1 = y0 + 1;
            const bool vx0 = (unsigned)x0 < WW;
            const bool vx1 = (unsigned)x1 < WW;
            const bool vy0 = (unsigned)y0 < HH;
            const bool vy1 = (unsigned)y1 < HH;
            const int cx0 = min(max(x0, 0), WW - 1);
            const int cx1 = min(max(x1, 0), WW - 1);
            const int cy0 = min(max(y0, 0), HH - 1);
            const int cy1 = min(max(y1, 0), HH - 1);
            w00[j] = (vx0 && vy0) ? wx0 * wy0 : 0.f;
            w01[j] = (vx1 && vy0) ? wx1 * wy0 : 0.f;
            w10[j] = (vx0 && vy1) ? wx0 * wy1 : 0.f;
            w11[j] = (vx1 && vy1) ? wx1 * wy1 : 0.f;
            i00[j] = cy0 * WW + cx0;
            i01[j] = cy0 * WW + cx1;
            i10[j] = cy1 * WW + cx0;
            i11[j] = cy1 * WW + cx1;
        }
        float v00[4], v01[4], v10[4], v11[4];
#pragma unroll
        for (int j = 0; j < 4; ++j) v00[j] = xp[i00[j]];
#pragma unroll
        for (int j = 0; j < 4; ++j) v01[j] = xp[i01[j]];
#pragma unroll
        for (int j = 0; j < 4; ++j) v10[j] = xp[i10[j]];
#pragma unroll
        for (int j = 0; j < 4; ++j) v11[j] = xp[i11[j]];
#pragma unroll
        for (int j = 0; j < 4; ++j) {
            float v = w00[j] * v00[j];
            v = fmaf(w01[j], v01[j], v);
            v = fmaf(w10[j], v10[j], v);
            v = fmaf(w11[j], v11[j], v);
            __builtin_nontemporal_store(v, &op[(k0 + j) * WW + w]);
        }
    }
}

extern "C" void kernel_launch(void* const* d_in, const int* in_sizes, int n_in,
                              void* d_out, int out_size, void* d_ws, size_t ws_size,
                              hipStream_t stream) {
    const float* x     = (const float*)d_in[0];
    const float* w_off = (const float*)d_in[1];
    const float* b_off = (const float*)d_in[2];
    float* out = (float*)d_out;

    if (ws_size >= NEED_WS) {
        unsigned int* xt = (unsigned int*)d_ws;
        float2* pq = (float2*)((char*)d_ws + XT_BYTES);
        k_prep<<<BB * HH, 256, 0, stream>>>(x, w_off, b_off, xt, pq);
        k_sample3<<<BB * HH * 4, 256, 0, stream>>>(xt, pq, out);
    } else {
        float2* pq = (float2*)d_ws;
        const int grid1 = (BB * HW / 4) / 256;
        k_offsets<<<grid1, 256, 0, stream>>>(x, w_off, b_off, pq);
        k_sample<<<BB * CC, 256, 0, stream>>>(x, pq, out);
    }
}

// Round 7
// 193.156 us; speedup vs baseline: 5.6667x; 1.0456x over previous
//
#include <hip/hip_runtime.h>

// x:     [B=16, C=64, H=256, W=256] float32
// w_off: [2, 64] float32
// b_off: [2] float32
// out:   [16, 64, 256, 256] float32
#define BB 16
#define CC 64
#define HH 256
#define WW 256
#define HW (HH * WW)

// ws layout: xt bf16 [B][H][W][C] = 16*65536*64*2 B = 134,217,728 B, then pq float2 (8 MiB)
#define XT_BYTES 134217728ULL
#define NEED_WS  (XT_BYTES + 8388608ULL)

typedef float    fx4 __attribute__((ext_vector_type(4)));   // native vecs for nontemporal stores
typedef unsigned ux4 __attribute__((ext_vector_type(4)));

__device__ __forceinline__ unsigned int f2bf(float f) {
    unsigned int u = __float_as_uint(f);
    u += 0x7FFFu + ((u >> 16) & 1u);          // round-to-nearest-even
    return u >> 16;
}
__device__ __forceinline__ float bflo(unsigned int w) { return __uint_as_float(w << 16); }
__device__ __forceinline__ float bfhi(unsigned int w) { return __uint_as_float(w & 0xFFFF0000u); }

// ---- kernel 1: read x coalesced; dot -> pq; bf16-pack + transpose -> xt[B,H,W,C] ----
// one block per (b,row). Pack to bf16 BEFORE LDS: s_pack[32][257] uints = 32.9 KB
// -> 4 blocks/CU (vs 2 with f32 staging). Store side: s_pack[k][t], lanes
// consecutive along t -> conflict-free. Read side: bank (4j+i + t>>3) -> max
// 2-way (free). xt written nontemporal (consumer is cross-XCD; L3 serves it).
__global__ __launch_bounds__(256) void k_prep(
    const float* __restrict__ x,
    const float* __restrict__ w_off,
    const float* __restrict__ b_off,
    unsigned int* __restrict__ xt,       // 32 uints (64 bf16) per pixel
    float2* __restrict__ pq)
{
    __shared__ unsigned int s_pack[CC / 2][WW + 1];
    __shared__ float sw0[CC], sw1[CC];
    const int t = threadIdx.x;
    if (t < CC)          sw0[t]      = w_off[t];
    else if (t < 2 * CC) sw1[t - CC] = w_off[t];
    __syncthreads();

    const int row = blockIdx.x & (HH - 1);
    const int b   = blockIdx.x >> 8;

    const float* __restrict__ xb = x + (size_t)b * CC * HW + row * WW + t;

    float a0 = 0.f, a1 = 0.f;
    float vprev = 0.f;
#pragma unroll 16
    for (int c = 0; c < CC; ++c) {
        const float v = xb[(size_t)c * HW];
        a0 = fmaf(v, sw0[c], a0);
        a1 = fmaf(v, sw1[c], a1);
        if (c & 1) s_pack[c >> 1][t] = f2bf(vprev) | (f2bf(v) << 16);
        vprev = v;
    }

    const float offx = tanhf(a0 + b_off[0]) * 0.5f;
    const float offy = tanhf(a1 + b_off[1]) * 0.5f;
    const float gx = -1.0f + (float)t   * (2.0f / (WW - 1)) + offx;
    const float gy = -1.0f + (float)row * (2.0f / (HH - 1)) + offy;
    const float px = ((gx + 1.0f) * (float)WW - 1.0f) * 0.5f;
    const float py = ((gy + 1.0f) * (float)HH - 1.0f) * 0.5f;
    pq[(size_t)b * HW + row * WW + t] = make_float2(px, py);

    __syncthreads();

    // write-out: thread t -> uint4 j = t&7 of pixel px = g*32 + (t>>3).
    // per wave-instruction: 1 KB contiguous (lanes cover 8 px x 8 uint4).
    const int j  = t & 7;
    const int pb = t >> 3;
    unsigned int* __restrict__ xto = xt + ((size_t)b * HW + (size_t)row * WW) * 32;
#pragma unroll
    for (int g = 0; g < 8; ++g) {
        const int p = g * 32 + pb;
        ux4 v;
        v.x = s_pack[4 * j + 0][p];
        v.y = s_pack[4 * j + 1][p];
        v.z = s_pack[4 * j + 2][p];
        v.w = s_pack[4 * j + 3][p];
        __builtin_nontemporal_store(v, reinterpret_cast<ux4*>(xto + (size_t)p * 32 + j * 4));
    }
}

// ---- kernel 2: lane-cooperative bilinear gather from bf16 xt (verified R6) ----
// 64-px blocks: grid 16384, XCD-chunked. Wave: 8 pixel-slots x 8 channel-octets;
// per pixel-corner the 8 lanes fetch one contiguous 128 B segment.
__global__ __launch_bounds__(256) void k_sample3(
    const unsigned int* __restrict__ xt,
    const float2* __restrict__ pq,
    float* __restrict__ out)
{
    const int raw = blockIdx.x;
    const int lb  = (raw & 7) * 2048 + (raw >> 3);   // bijective XCD chunking
    const int quarter = lb & 3;
    const int row     = (lb >> 2) & (HH - 1);
    const int b       = lb >> 10;

    __shared__ float so[CC][65];     // [channel][pixel], bank = (c+px)%32 both ways

    const int t  = threadIdx.x;
    const int l8 = t & 7;            // channel octet: channels l8*8 .. +7
    const int ps = t >> 3;           // pixel slot 0..31
    const int px0 = quarter * 64;

    const unsigned int* __restrict__ xb = xt + (size_t)b * HW * 32;
    const float2* __restrict__ pqr = pq + (size_t)b * HW + row * WW + px0;

    const int pxlA = ps;
    const int pxlB = 32 + ps;
    const float2 prA = pqr[pxlA];
    const float2 prB = pqr[pxlB];

#define COORDS(pr, W00, W01, W10, W11, I00, I01, I10, I11)                          \
    {                                                                               \
        const float x0f = floorf(pr.x), y0f = floorf(pr.y);                         \
        const float wx1 = pr.x - x0f,  wy1 = pr.y - y0f;                            \
        const float wx0 = 1.f - wx1,   wy0 = 1.f - wy1;                             \
        const int x0 = (int)x0f, y0 = (int)y0f, x1 = x0 + 1, y1 = y0 + 1;           \
        const bool vx0 = (unsigned)x0 < WW, vx1 = (unsigned)x1 < WW;                \
        const bool vy0 = (unsigned)y0 < HH, vy1 = (unsigned)y1 < HH;                \
        const int cx0 = min(max(x0, 0), WW - 1), cx1 = min(max(x1, 0), WW - 1);     \
        const int cy0 = min(max(y0, 0), HH - 1), cy1 = min(max(y1, 0), HH - 1);     \
        W00 = (vx0 && vy0) ? wx0 * wy0 : 0.f;                                       \
        W01 = (vx1 && vy0) ? wx1 * wy0 : 0.f;                                       \
        W10 = (vx0 && vy1) ? wx0 * wy1 : 0.f;                                       \
        W11 = (vx1 && vy1) ? wx1 * wy1 : 0.f;                                       \
        I00 = (size_t)(cy0 * WW + cx0) * 32 + l8 * 4;                               \
        I01 = (size_t)(cy0 * WW + cx1) * 32 + l8 * 4;                               \
        I10 = (size_t)(cy1 * WW + cx0) * 32 + l8 * 4;                               \
        I11 = (size_t)(cy1 * WW + cx1) * 32 + l8 * 4;                               \
    }

    float wA00, wA01, wA10, wA11, wB00, wB01, wB10, wB11;
    size_t iA00, iA01, iA10, iA11, iB00, iB01, iB10, iB11;
    COORDS(prA, wA00, wA01, wA10, wA11, iA00, iA01, iA10, iA11)
    COORDS(prB, wB00, wB01, wB10, wB11, iB00, iB01, iB10, iB11)

    // issue all 8 cooperative gathers (128 B per pixel-corner)
    const uint4 vA00 = *reinterpret_cast<const uint4*>(xb + iA00);
    const uint4 vA01 = *reinterpret_cast<const uint4*>(xb + iA01);
    const uint4 vA10 = *reinterpret_cast<const uint4*>(xb + iA10);
    const uint4 vA11 = *reinterpret_cast<const uint4*>(xb + iA11);
    const uint4 vB00 = *reinterpret_cast<const uint4*>(xb + iB00);
    const uint4 vB01 = *reinterpret_cast<const uint4*>(xb + iB01);
    const uint4 vB10 = *reinterpret_cast<const uint4*>(xb + iB10);
    const uint4 vB11 = *reinterpret_cast<const uint4*>(xb + iB11);

    const int c8 = l8 * 8;

#define BLEND_STORE(V00, V01, V10, V11, W00, W01, W10, W11, PXL)                    \
    {                                                                               \
        float f0 = W00 * bflo(V00.x); float f1 = W00 * bfhi(V00.x);                 \
        float f2 = W00 * bflo(V00.y); float f3 = W00 * bfhi(V00.y);                 \
        float f4 = W00 * bflo(V00.z); float f5 = W00 * bfhi(V00.z);                 \
        float f6 = W00 * bflo(V00.w); float f7 = W00 * bfhi(V00.w);                 \
        f0 = fmaf(W01, bflo(V01.x), f0); f1 = fmaf(W01, bfhi(V01.x), f1);           \
        f2 = fmaf(W01, bflo(V01.y), f2); f3 = fmaf(W01, bfhi(V01.y), f3);           \
        f4 = fmaf(W01, bflo(V01.z), f4); f5 = fmaf(W01, bfhi(V01.z), f5);           \
        f6 = fmaf(W01, bflo(V01.w), f6); f7 = fmaf(W01, bfhi(V01.w), f7);           \
        f0 = fmaf(W10, bflo(V10.x), f0); f1 = fmaf(W10, bfhi(V10.x), f1);           \
        f2 = fmaf(W10, bflo(V10.y), f2); f3 = fmaf(W10, bfhi(V10.y), f3);           \
        f4 = fmaf(W10, bflo(V10.z), f4); f5 = fmaf(W10, bfhi(V10.z), f5);           \
        f6 = fmaf(W10, bflo(V10.w), f6); f7 = fmaf(W10, bfhi(V10.w), f7);           \
        f0 = fmaf(W11, bflo(V11.x), f0); f1 = fmaf(W11, bfhi(V11.x), f1);           \
        f2 = fmaf(W11, bflo(V11.y), f2); f3 = fmaf(W11, bfhi(V11.y), f3);           \
        f4 = fmaf(W11, bflo(V11.z), f4); f5 = fmaf(W11, bfhi(V11.z), f5);           \
        f6 = fmaf(W11, bflo(V11.w), f6); f7 = fmaf(W11, bfhi(V11.w), f7);           \
        so[c8 + 0][PXL] = f0; so[c8 + 1][PXL] = f1;                                 \
        so[c8 + 2][PXL] = f2; so[c8 + 3][PXL] = f3;                                 \
        so[c8 + 4][PXL] = f4; so[c8 + 5][PXL] = f5;                                 \
        so[c8 + 6][PXL] = f6; so[c8 + 7][PXL] = f7;                                 \
    }

    BLEND_STORE(vA00, vA01, vA10, vA11, wA00, wA01, wA10, wA11, pxlA)
    BLEND_STORE(vB00, vB01, vB10, vB11, wB00, wB01, wB10, wB11, pxlB)

    __syncthreads();

    // coalesced write-out: float4 along w, 4 channel segments per instr
    const int p  = t & 15;          // pixel quad 4p..4p+3
    const int cg = (t >> 4) & 3;
    const int wv = t >> 6;
    float* __restrict__ ob = out + (size_t)b * CC * HW + row * WW + px0;
#pragma unroll
    for (int it = 0; it < 4; ++it) {
        const int c = wv * 16 + it * 4 + cg;
        fx4 r;
        r.x = so[c][4 * p + 0];
        r.y = so[c][4 * p + 1];
        r.z = so[c][4 * p + 2];
        r.w = so[c][4 * p + 3];
        __builtin_nontemporal_store(r, reinterpret_cast<fx4*>(ob + (size_t)c * HW + 4 * p));
    }
}

// ============================ FALLBACK PATH (R3, verified) ============================
__global__ __launch_bounds__(256) void k_offsets(
    const float* __restrict__ x,
    const float* __restrict__ w_off,
    const float* __restrict__ b_off,
    float2* __restrict__ pq)
{
    __shared__ float s_w0[CC];
    __shared__ float s_w1[CC];
    if (threadIdx.x < CC)          s_w0[threadIdx.x]      = w_off[threadIdx.x];
    else if (threadIdx.x < 2 * CC) s_w1[threadIdx.x - CC] = w_off[threadIdx.x];
    __syncthreads();

    const int t    = blockIdx.x * blockDim.x + threadIdx.x;
    const int pix0 = t * 4;
    const int w = pix0 & (WW - 1);
    const int h = (pix0 >> 8) & (HH - 1);
    const int b = pix0 >> 16;

    const float* __restrict__ xb = x + (size_t)b * CC * HW + h * WW + w;

    float a0[4] = {0.f, 0.f, 0.f, 0.f};
    float a1[4] = {0.f, 0.f, 0.f, 0.f};
#pragma unroll 8
    for (int c = 0; c < CC; ++c) {
        const float4 v = *reinterpret_cast<const float4*>(xb + (size_t)c * HW);
        const float w0 = s_w0[c], w1 = s_w1[c];
        a0[0] = fmaf(v.x, w0, a0[0]); a1[0] = fmaf(v.x, w1, a1[0]);
        a0[1] = fmaf(v.y, w0, a0[1]); a1[1] = fmaf(v.y, w1, a1[1]);
        a0[2] = fmaf(v.z, w0, a0[2]); a1[2] = fmaf(v.z, w1, a1[2]);
        a0[3] = fmaf(v.w, w0, a0[3]); a1[3] = fmaf(v.w, w1, a1[3]);
    }

    const float b0 = b_off[0], b1 = b_off[1];
#pragma unroll
    for (int j = 0; j < 4; ++j) {
        const float offx = tanhf(a0[j] + b0) * 0.5f;
        const float offy = tanhf(a1[j] + b1) * 0.5f;
        const float gx = -1.0f + (float)(w + j) * (2.0f / (WW - 1)) + offx;
        const float gy = -1.0f + (float)h       * (2.0f / (HH - 1)) + offy;
        const float px = ((gx + 1.0f) * (float)WW - 1.0f) * 0.5f;
        const float py = ((gy + 1.0f) * (float)HH - 1.0f) * 0.5f;
        pq[pix0 + j] = make_float2(px, py);
    }
}

__global__ __launch_bounds__(256, 4) void k_sample(
    const float* __restrict__ x,
    const float2* __restrict__ pq,
    float* __restrict__ out)
{
    const int bid = blockIdx.x;
    const int c = bid & (CC - 1);
    const int b = bid >> 6;

    const float* __restrict__ xp = x   + ((size_t)b * CC + c) * HW;
    float* __restrict__       op = out + ((size_t)b * CC + c) * HW;
    const float2* __restrict__ pqb = pq + (size_t)b * HW;

    const int w = threadIdx.x;

    for (int k0 = 0; k0 < HH; k0 += 4) {
        int   i00[4], i01[4], i10[4], i11[4];
        float w00[4], w01[4], w10[4], w11[4];
#pragma unroll
        for (int j = 0; j < 4; ++j) {
            const float2 p = pqb[(k0 + j) * WW + w];
            const float x0f = floorf(p.x);
            const float y0f = floorf(p.y);
            const float wx1 = p.x - x0f;
            const float wy1 = p.y - y0f;
            const float wx0 = 1.0f - wx1;
            const float wy0 = 1.0f - wy1;
            const int x0 = (int)x0f, y0 = (int)y0f;
            const int x1 = x0 + 1,   y1 = y0 + 1;
            const bool vx0 = (unsigned)x0 < WW;
            const bool vx1 = (unsigned)x1 < WW;
            const bool vy0 = (unsigned)y0 < HH;
            const bool vy1 = (unsigned)y1 < HH;
            const int cx0 = min(max(x0, 0), WW - 1);
            const int cx1 = min(max(x1, 0), WW - 1);
            const int cy0 = min(max(y0, 0), HH - 1);
            const int cy1 = min(max(y1, 0), HH - 1);
            w00[j] = (vx0 && vy0) ? wx0 * wy0 : 0.f;
            w01[j] = (vx1 && vy0) ? wx1 * wy0 : 0.f;
            w10[j] = (vx0 && vy1) ? wx0 * wy1 : 0.f;
            w11[j] = (vx1 && vy1) ? wx1 * wy1 : 0.f;
            i00[j] = cy0 * WW + cx0;
            i01[j] = cy0 * WW + cx1;
            i10[j] = cy1 * WW + cx0;
            i11[j] = cy1 * WW + cx1;
        }
        float v00[4], v01[4], v10[4], v11[4];
#pragma unroll
        for (int j = 0; j < 4; ++j) v00[j] = xp[i00[j]];
#pragma unroll
        for (int j = 0; j < 4; ++j) v01[j] = xp[i01[j]];
#pragma unroll
        for (int j = 0; j < 4; ++j) v10[j] = xp[i10[j]];
#pragma unroll
        for (int j = 0; j < 4; ++j) v11[j] = xp[i11[j]];
#pragma unroll
        for (int j = 0; j < 4; ++j) {
            float v = w00[j] * v00[j];
            v = fmaf(w01[j], v01[j], v);
            v = fmaf(w10[j], v10[j], v);
            v = fmaf(w11[j], v11[j], v);
            __builtin_nontemporal_store(v, &op[(k0 + j) * WW + w]);
        }
    }
}

extern "C" void kernel_launch(void* const* d_in, const int* in_sizes, int n_in,
                              void* d_out, int out_size, void* d_ws, size_t ws_size,
                              hipStream_t stream) {
    const float* x     = (const float*)d_in[0];
    const float* w_off = (const float*)d_in[1];
    const float* b_off = (const float*)d_in[2];
    float* out = (float*)d_out;

    if (ws_size >= NEED_WS) {
        unsigned int* xt = (unsigned int*)d_ws;
        float2* pq = (float2*)((char*)d_ws + XT_BYTES);
        k_prep<<<BB * HH, 256, 0, stream>>>(x, w_off, b_off, xt, pq);
        k_sample3<<<BB * HH * 4, 256, 0, stream>>>(xt, pq, out);
    } else {
        float2* pq = (float2*)d_ws;
        const int grid1 = (BB * HW / 4) / 256;
        k_offsets<<<grid1, 256, 0, stream>>>(x, w_off, b_off, pq);
        k_sample<<<BB * CC, 256, 0, stream>>>(x, pq, out);
    }
}